// Round 11
// baseline (519.261 us; speedup 1.0000x reference)
//
#include <hip/hip_runtime.h>
#include <stdint.h>

// ---------------------------------------------------------------------------
// CPMAntAttention: B=2,S=1024,D=4096,H=32,DH=128
// Round 11: attn occupancy play — single-buffered K/V LDS (41KB total ->
// 3 blocks/CU = 12 waves/CU, was 2/8), strictly serial per-tile with TLP
// covering the stage drain. launch_bounds(256,3) (state ~130 VGPR < 170 cap,
// no r7-style spill). Swapped-QK^T compute kept from r10. GEMMs identical.
// ---------------------------------------------------------------------------

#define B_  2
#define S_  1024
#define D_  4096
#define H_  32
#define DH_ 128
#define M_  (B_ * S_)          // 2048
#define KSTR 8192              // row stride of fused KV output

typedef __attribute__((ext_vector_type(8))) short bf16x8;
typedef __attribute__((ext_vector_type(4))) float f32x4;

static __device__ __forceinline__ unsigned short f32_to_bf16(float f) {
    unsigned int x = __float_as_uint(f);
    x += 0x7fffu + ((x >> 16) & 1u);   // RNE
    return (unsigned short)(x >> 16);
}

static __device__ __forceinline__ f32x4 mfma16(bf16x8 a, bf16x8 b, f32x4 c) {
    return __builtin_amdgcn_mfma_f32_16x16x32_bf16(a, b, c, 0, 0, 0);
}

#if defined(__has_builtin)
#if __has_builtin(__builtin_amdgcn_global_load_lds)
#define HAVE_GLOAD_LDS 1
#endif
#endif

#ifdef HAVE_GLOAD_LDS
#define GLD16(g, lbase, lane)                                                  \
    __builtin_amdgcn_global_load_lds(                                          \
        (const __attribute__((address_space(1))) void*)(g),                    \
        (__attribute__((address_space(3))) void*)(lbase), 16, 0, 0)
#else
#define GLD16(g, lbase, lane)                                                  \
    do { *(bf16x8*)((unsigned short*)(lbase) + (size_t)(lane) * 8) =           \
             *(const bf16x8*)(g); } while (0)
#endif

// ---------------------------------------------------------------------------
__global__ void detect_mask_kernel(const unsigned char* __restrict__ m, int* flag) {
    int l = threadIdx.x;
    uint4 v = ((const uint4*)m)[l];
    unsigned int ww[4] = {v.x, v.y, v.z, v.w};
    int nz_hi = 0, nz_lo01 = 0;
#pragma unroll
    for (int wi = 0; wi < 4; ++wi)
#pragma unroll
        for (int bi = 0; bi < 4; ++bi) {
            unsigned int byte = (ww[wi] >> (bi * 8)) & 0xffu;
            if (byte && bi != 0) nz_hi = 1;
            if (byte && bi <= 1) nz_lo01 = 1;
        }
    int any_hi = __any(nz_hi);
    int any_lo01 = __any(nz_lo01);
    if (l == 0) *flag = (!any_hi) ? 1 : ((!any_lo01) ? 2 : 0);
}

__global__ void canon_mask_kernel(const void* __restrict__ m, const int* __restrict__ flag,
                                  unsigned char* __restrict__ out, int n) {
    int i = blockIdx.x * 256 + threadIdx.x;
    if (i >= n) return;
    int f = *flag;
    unsigned char v;
    if (f == 1)      v = (unsigned char)(((const int*)m)[i] != 0);
    else if (f == 2) v = (unsigned char)(((const float*)m)[i] != 0.0f);
    else             v = (unsigned char)(((const unsigned char*)m)[i] != 0);
    out[i] = v;
}

__global__ void cvt2_bf16_kernel(const float* __restrict__ a, const float* __restrict__ b,
                                 unsigned short* __restrict__ oa, unsigned short* __restrict__ ob) {
    int i = blockIdx.x * 256 + threadIdx.x;
    const int n4 = (B_ * S_ * D_) / 4;
    const float* src = (i < n4) ? a : b;
    unsigned short* dst = (i < n4) ? oa : ob;
    int j = (i < n4) ? i : i - n4;
    float4 v = ((const float4*)src)[j];
    ushort4 o;
    o.x = f32_to_bf16(v.x); o.y = f32_to_bf16(v.y);
    o.z = f32_to_bf16(v.z); o.w = f32_to_bf16(v.w);
    ((ushort4*)dst)[j] = o;
}

__global__ __launch_bounds__(256) void transpose_all_kernel(
        const float* __restrict__ Wq, const float* __restrict__ Wk,
        const float* __restrict__ Wv, const float* __restrict__ Wo,
        unsigned short* __restrict__ WTq, unsigned short* __restrict__ WTkv,
        unsigned short* __restrict__ WTo) {
    __shared__ unsigned short lds[64][65];
    int which = blockIdx.x >> 12;
    int bid = blockIdx.x & 4095;
    const float* W = (which == 0) ? Wq : (which == 1) ? Wk : (which == 2) ? Wv : Wo;
    unsigned short* WT = (which == 0) ? WTq
                       : (which == 1) ? WTkv
                       : (which == 2) ? (WTkv + (size_t)4096 * 4096)
                                      : WTo;
    int bx = bid & 63;
    int by = bid >> 6;
    int t = threadIdx.x;
    int tr = t >> 4;
    int tc = (t & 15) * 4;
#pragma unroll
    for (int p = 0; p < 4; ++p) {
        int r = p * 16 + tr;
        float4 v = *(const float4*)(W + (size_t)(by * 64 + r) * D_ + bx * 64 + tc);
        lds[r][tc + 0] = f32_to_bf16(v.x);
        lds[r][tc + 1] = f32_to_bf16(v.y);
        lds[r][tc + 2] = f32_to_bf16(v.z);
        lds[r][tc + 3] = f32_to_bf16(v.w);
    }
    __syncthreads();
#pragma unroll
    for (int p = 0; p < 4; ++p) {
        int n = p * 16 + tr;
        ushort4 o;
        o.x = lds[tc + 0][n]; o.y = lds[tc + 1][n];
        o.z = lds[tc + 2][n]; o.w = lds[tc + 3][n];
        *(ushort4*)(WT + (size_t)(bx * 64 + n) * D_ + by * 64 + tc) = o;
    }
}

__global__ __launch_bounds__(256) void vt_kernel(const unsigned short* __restrict__ KV,
                                                 unsigned short* __restrict__ Vtw) {
    __shared__ unsigned short lds[64][72];
    int bid = blockIdx.x;
    int dt = bid & 1;
    int st = (bid >> 1) & 15;
    int h  = (bid >> 5) & 31;
    int b  = bid >> 10;
    int t = threadIdx.x;
    int r = t >> 2;
    int c0 = (t & 3) * 16;
    const unsigned short* src =
        KV + (size_t)(b * S_ + st * 64 + r) * KSTR + 4096 + h * DH_ + dt * 64 + c0;
    bf16x8 v0 = *(const bf16x8*)(src);
    bf16x8 v1 = *(const bf16x8*)(src + 8);
    *(bf16x8*)&lds[r][c0] = v0;
    *(bf16x8*)&lds[r][c0 + 8] = v1;
    __syncthreads();
    unsigned short tmp[16];
#pragma unroll
    for (int i = 0; i < 16; ++i) tmp[i] = lds[c0 + i][r];
    unsigned short* dst =
        Vtw + ((size_t)((b * H_ + h) * DH_ + dt * 64 + r)) * S_ + st * 64 + c0;
    *(bf16x8*)dst = *(bf16x8*)&tmp[0];
    *(bf16x8*)(dst + 8) = *(bf16x8*)&tmp[8];
}

// ---------------------------------------------------------------------------
// Phase-pipelined GEMM core (r6, unchanged). Tile 256x256, BK=64, 512 thr.
__device__ __forceinline__ void gemm_core(const unsigned short* __restrict__ A,
                                          const unsigned short* __restrict__ BT,
                                          void* __restrict__ C, int out_f32,
                                          int m0, int n0, int cstride,
                                          int koff, int NT, char* ldsc) {
    const int t = threadIdx.x;
    const int w = t >> 6, l = t & 63;
    const int lr = l & 15, lg = l >> 4;
    const int wmh = w >> 2;              // A half select (0/1)
    const int walf = w & 3;
    const int wm = wmh << 7;             // 0/128
    const int wn = walf << 6;            // 0..192

    const int ca0 = lg ^ (lr & 7);
    const int aoff0 = lr * 128 + (ca0 << 4);
    const int aoff1 = lr * 128 + ((ca0 ^ 4) << 4);
    const int boff0 = ((walf & 1) * 64 + lr) * 128 + (ca0 << 4);
    const int boff1 = ((walf & 1) * 64 + lr) * 128 + ((ca0 ^ 4) << 4);

    const int srow = t >> 3;
    const int sch = (t & 7) ^ (srow & 7);
    const size_t soff0 = (size_t)srow * 4096 + (size_t)(sch << 3);
    const size_t soff1 = soff0 + (size_t)64 * 4096;
    const int ldso = w << 10;            // per-wave BYTE offset

    f32x4 ac[8][4];
    f32x4 vzero = {0.f, 0.f, 0.f, 0.f};
#pragma unroll
    for (int i = 0; i < 8; ++i)
#pragma unroll
        for (int j = 0; j < 4; ++j) ac[i][j] = vzero;

#define STAGE_ELEM(E, SS)                                                      \
    do {                                                                       \
        int er_ = (E) & 3;                                                     \
        const unsigned short* mb_ = (er_ < 2)                                  \
            ? A + (size_t)(m0 + ((er_ & 1) << 7)) * 4096                       \
            : BT + (size_t)(n0 + ((er_ & 1) << 7)) * 4096;                     \
        mb_ += (size_t)((((E) >> 2) << 6) + koff);                             \
        char* d0_ = ldsc + (SS) * 16384 + ldso;                                \
        GLD16(mb_ + soff0, d0_, l);                                            \
        GLD16(mb_ + soff1, d0_ + 8192, l);                                     \
    } while (0)

#pragma unroll
    for (int e = 0; e < 5; ++e) STAGE_ELEM(e, e);

    const int NT4 = NT << 2;
    int E = 5, ss = 5, s0 = 0;
    bf16x8 bfr[4][2];

#pragma unroll 1
    for (int tau = 0; tau < NT; ++tau) {
        int sA = s0 + wmh;          if (sA >= 9) sA -= 9;
        int sB = s0 + 2 + (walf >> 1); if (sB >= 9) sB -= 9;
        const char* pA0 = ldsc + sA * 16384 + aoff0;
        const char* pA1 = ldsc + sA * 16384 + aoff1;
        const char* pB0 = ldsc + sB * 16384 + boff0;
        const char* pB1 = ldsc + sB * 16384 + boff1;
#pragma unroll
        for (int r = 0; r < 4; ++r) {
            if (r == 0) {
                if (tau == NT - 1)
                    asm volatile("s_waitcnt vmcnt(0)" ::: "memory");
                else
                    asm volatile("s_waitcnt vmcnt(2)" ::: "memory");
            }
            __builtin_amdgcn_s_barrier();
            asm volatile("" ::: "memory");
            if (r == 0) {
#pragma unroll
                for (int nf = 0; nf < 4; ++nf) {
                    bfr[nf][0] = *(const bf16x8*)(pB0 + nf * 2048);
                    bfr[nf][1] = *(const bf16x8*)(pB1 + nf * 2048);
                }
            }
            bf16x8 af[2][2];
            int mfb = r << 1;
#pragma unroll
            for (int j = 0; j < 2; ++j) {
                af[j][0] = *(const bf16x8*)(pA0 + (mfb + j) * 2048);
                af[j][1] = *(const bf16x8*)(pA1 + (mfb + j) * 2048);
            }
            if (E < NT4) STAGE_ELEM(E, ss);
            ++E; ss = (ss == 8) ? 0 : ss + 1;
            __builtin_amdgcn_s_setprio(1);
#pragma unroll
            for (int j = 0; j < 2; ++j)
#pragma unroll
                for (int nf = 0; nf < 4; ++nf) {
                    ac[mfb + j][nf] = mfma16(af[j][0], bfr[nf][0], ac[mfb + j][nf]);
                    ac[mfb + j][nf] = mfma16(af[j][1], bfr[nf][1], ac[mfb + j][nf]);
                }
            __builtin_amdgcn_s_setprio(0);
        }
        s0 += 4; if (s0 >= 9) s0 -= 9;
    }
#undef STAGE_ELEM

#pragma unroll
    for (int mf = 0; mf < 8; ++mf)
#pragma unroll
        for (int nf = 0; nf < 4; ++nf)
#pragma unroll
            for (int q = 0; q < 4; ++q) {
                int row = m0 + wm + mf * 16 + lg * 4 + q;
                int col = n0 + wn + nf * 16 + lr;
                if (out_f32)
                    ((float*)C)[(size_t)row * cstride + col] = ac[mf][nf][q];
                else
                    ((unsigned short*)C)[(size_t)row * cstride + col] = f32_to_bf16(ac[mf][nf][q]);
            }
}

// 512 blocks, two homogeneous rounds (r9): 0..255 KV full-K, 256..511 Q splitK2.
__global__ __launch_bounds__(512, 2) void gemm_qkv_kernel(
        const unsigned short* __restrict__ Aq, const unsigned short* __restrict__ Bq,
        float* __restrict__ Pq,
        const unsigned short* __restrict__ Akv, const unsigned short* __restrict__ Bkv,
        unsigned short* __restrict__ Ckv) {
    __shared__ char ldsbuf[9 * 16384];
    int bid = blockIdx.x;
    if (bid < 256) {
        int bm = bid & 7, bn = bid >> 3;
        gemm_core(Akv, Bkv, Ckv, 0, bm << 8, bn << 8, 8192, 0, 64, ldsbuf);
    } else {
        int e = bid - 256;
        int bm = e & 7;
        int rest = e >> 3;
        int bn = rest & 15;
        int ks = rest >> 4;
        gemm_core(Aq, Bq, Pq + (size_t)ks * M_ * D_, 1, bm << 8, bn << 8, 4096,
                  ks * 2048, 32, ldsbuf);
    }
}

__global__ void reduce_q_kernel(const float* __restrict__ P, unsigned short* __restrict__ out) {
    int i = blockIdx.x * 256 + threadIdx.x;
    float4 a = ((const float4*)P)[i];
    float4 b = ((const float4*)(P + (size_t)M_ * D_))[i];
    ushort4 o;
    o.x = f32_to_bf16(a.x + b.x); o.y = f32_to_bf16(a.y + b.y);
    o.z = f32_to_bf16(a.z + b.z); o.w = f32_to_bf16(a.w + b.w);
    ((ushort4*)out)[i] = o;
}

__global__ __launch_bounds__(512, 2) void gemm_o_kernel(
        const unsigned short* __restrict__ A, const unsigned short* __restrict__ BT,
        float* __restrict__ P) {
    __shared__ char ldsbuf[9 * 16384];
    int bid = blockIdx.x;
    int bm = bid & 7;
    int rest = bid >> 3;
    int bn = rest & 15;
    int ks = rest >> 4;
    gemm_core(A, BT, P + (size_t)ks * M_ * D_, 1, bm << 8, bn << 8, 4096,
              ks * 2048, 32, ldsbuf);
}

__global__ void reduce_o_kernel(const float* __restrict__ P, float* __restrict__ out) {
    int i = blockIdx.x * 256 + threadIdx.x;
    float4 a = ((const float4*)P)[i];
    float4 b = ((const float4*)(P + (size_t)M_ * D_))[i];
    float4 o; o.x = a.x + b.x; o.y = a.y + b.y; o.z = a.z + b.z; o.w = a.w + b.w;
    ((float4*)out)[i] = o;
}

// ---------------------------------------------------------------------------
// Flash attention, round 11: single-buffered K/V (41KB LDS -> 3 blocks/CU,
// 12 waves/CU), serial per-tile, TLP hides stage drain. Swapped QK^T (r10).
#define NEGF (-1e30f)
__global__ __launch_bounds__(256, 3) void attn_kernel(const unsigned short* __restrict__ Qw,
                                                      const unsigned short* __restrict__ KV,
                                                      const unsigned short* __restrict__ Vtw,
                                                      const float* __restrict__ bias,
                                                      const unsigned char* __restrict__ maskc,
                                                      unsigned short* __restrict__ ctx) {
    __shared__ unsigned short Kbuf[64 * 128];    // 16KB, chunk^=(krow&7)
    __shared__ unsigned short Vbuf[128 * 64];    // 16KB, chunk^=(vrow&7)
    __shared__ unsigned short Plds[4][16 * 72];  // 9KB

    int bid = blockIdx.x;
    int qt = bid & 15, h = (bid >> 4) & 31, b = bid >> 9;
    int t = threadIdx.x, w = t >> 6, l = t & 63;
    int lr = l & 15, lg = l >> 4;
    int q0 = (qt << 6) + (w << 4);

    bf16x8 qf[4];
    const unsigned short* Qp = Qw + ((size_t)(b * S_ + q0 + lr)) * D_ + h * DH_ + lg * 8;
#pragma unroll
    for (int kf = 0; kf < 4; ++kf) qf[kf] = *(const bf16x8*)(Qp + kf * 32);

    f32x4 o[8];
    f32x4 vzero = {0.f, 0.f, 0.f, 0.f};
#pragma unroll
    for (int i = 0; i < 8; ++i) o[i] = vzero;
    float m_run = NEGF, l_run = 0.f;     // per-lane: q-row = q0 + lr

    const float* biasp = bias + (((size_t)(b * H_ + h)) << 20)
                              + (((size_t)(q0 + lr)) << 10);
    const unsigned char* mp = maskc + ((size_t)b << 20)
                              + (((size_t)(q0 + lr)) << 10);
    const unsigned short* Kg = KV + (size_t)(b * S_) * KSTR + h * DH_;
    const unsigned short* Vg = Vtw + (((size_t)(b * H_ + h)) * DH_) * S_;

    float4 br[4];
    unsigned int mr[4];

#define STAGE_KV(KT)                                                               \
    do { int kv0_ = (KT) << 6;                                                     \
        _Pragma("unroll")                                                          \
        for (int c = 0; c < 4; ++c) {                                              \
            int seg = (w << 2) + c;                                                \
            int krow = (seg << 2) + (l >> 4);                                      \
            int kch = (l & 15) ^ (krow & 7);                                       \
            GLD16(Kg + (size_t)(kv0_ + krow) * KSTR + (kch << 3),                  \
                  &Kbuf[seg << 9], l);                                             \
            int vrow = (seg << 3) + (l >> 3);                                      \
            int vch = (l & 7) ^ (vrow & 7);                                        \
            GLD16(Vg + (size_t)vrow * S_ + kv0_ + (vch << 3),                      \
                  &Vbuf[seg << 9], l);                                             \
        }                                                                          \
    } while (0)

#define LOAD_BM(KT)                                                                \
    do { int kv0_ = (KT) << 6;                                                     \
        _Pragma("unroll")                                                          \
        for (int nb = 0; nb < 4; ++nb) {                                           \
            br[nb] = *(const float4*)(biasp + kv0_ + (nb << 4) + (lg << 2));       \
            mr[nb] = *(const unsigned int*)(mp + kv0_ + (nb << 4) + (lg << 2));    \
        }                                                                          \
    } while (0)

#define COMPUTE()                                                                  \
    do {                                                                           \
        f32x4 s_[4];                                                               \
        __builtin_amdgcn_s_setprio(1);                                             \
        _Pragma("unroll")                                                          \
        for (int nb = 0; nb < 4; ++nb) {                                           \
            s_[nb] = vzero;                                                        \
            int krow = (nb << 4) + lr;                                             \
            _Pragma("unroll")                                                      \
            for (int kf = 0; kf < 4; ++kf) {                                       \
                int ba = ((krow << 8) + (((kf << 5) + (lg << 3)) << 1))            \
                         ^ ((krow & 7) << 4);                                      \
                bf16x8 kfr = *(const bf16x8*)((const char*)Kbuf + ba);             \
                s_[nb] = mfma16(kfr, qf[kf], s_[nb]);                              \
            }                                                                      \
        }                                                                          \
        __builtin_amdgcn_s_setprio(0);                                             \
        float sv[4][4];                                                            \
        _Pragma("unroll")                                                          \
        for (int nb = 0; nb < 4; ++nb) {                                           \
            float bb[4] = {br[nb].x, br[nb].y, br[nb].z, br[nb].w};                \
            _Pragma("unroll")                                                      \
            for (int r = 0; r < 4; ++r) {                                          \
                float x = fmaf(s_[nb][r], 0.08838834764831845f, bb[r]);            \
                sv[nb][r] = ((mr[nb] >> (r * 8)) & 0xffu) ? x : NEGF;              \
            }                                                                      \
        }                                                                          \
        float mt = sv[0][0];                                                       \
        _Pragma("unroll")                                                          \
        for (int nb = 0; nb < 4; ++nb)                                             \
            _Pragma("unroll")                                                      \
            for (int r = 0; r < 4; ++r) mt = fmaxf(mt, sv[nb][r]);                 \
        mt = fmaxf(mt, __shfl_xor(mt, 16, 64));                                    \
        mt = fmaxf(mt, __shfl_xor(mt, 32, 64));                                    \
        float mn = fmaxf(m_run, mt);                                               \
        float al = __expf(m_run - mn);                                             \
        m_run = mn;                                                                \
        float rs = 0.f;                                                            \
        _Pragma("unroll")                                                          \
        for (int nb = 0; nb < 4; ++nb)                                             \
            _Pragma("unroll")                                                      \
            for (int r = 0; r < 4; ++r) {                                          \
                sv[nb][r] = __expf(sv[nb][r] - m_run);                             \
                rs += sv[nb][r];                                                   \
            }                                                                      \
        rs += __shfl_xor(rs, 16, 64);                                              \
        rs += __shfl_xor(rs, 32, 64);                                              \
        l_run = l_run * al + rs;                                                   \
        float alm[4];                                                              \
        _Pragma("unroll")                                                          \
        for (int r = 0; r < 4; ++r) alm[r] = __shfl(al, (lg << 2) + r, 64);        \
        _Pragma("unroll")                                                          \
        for (int nb2 = 0; nb2 < 8; ++nb2) {                                        \
            o[nb2][0] *= alm[0]; o[nb2][1] *= alm[1];                              \
            o[nb2][2] *= alm[2]; o[nb2][3] *= alm[3];                              \
        }                                                                          \
        _Pragma("unroll")                                                          \
        for (int nb = 0; nb < 4; ++nb)                                             \
            _Pragma("unroll")                                                      \
            for (int r = 0; r < 4; ++r)                                            \
                Plds[w][lr * 72 + (nb << 4) + (lg << 2) + r] = f32_to_bf16(sv[nb][r]); \
        __builtin_amdgcn_s_setprio(1);                                             \
        _Pragma("unroll")                                                          \
        for (int kf2 = 0; kf2 < 2; ++kf2) {                                        \
            bf16x8 pf = *(const bf16x8*)&Plds[w][lr * 72 + (kf2 << 5) + (lg << 3)]; \
            _Pragma("unroll")                                                      \
            for (int nb2 = 0; nb2 < 8; ++nb2) {                                    \
                int dh = (nb2 << 4) + lr;                                          \
                int ba = ((dh << 7) + (((kf2 << 5) + (lg << 3)) << 1))             \
                         ^ ((dh & 7) << 4);                                        \
                bf16x8 vf = *(const bf16x8*)((const char*)Vbuf + ba);              \
                o[nb2] = mfma16(pf, vf, o[nb2]);                                   \
            }                                                                      \
        }                                                                          \
        __builtin_amdgcn_s_setprio(0);                                             \
    } while (0)

    STAGE_KV(0);
    LOAD_BM(0);

#pragma unroll 1
    for (int kt = 0; kt < 16; ++kt) {
        __syncthreads();             // stage kt (+bias kt) drained into LDS/regs
        COMPUTE();                   // tile kt
        __syncthreads();             // all waves done reading Kbuf/Vbuf
        if (kt < 15) {
            STAGE_KV(kt + 1);
            LOAD_BM(kt + 1);
        }
    }

    // epilogue: l for row (lg<<2)+r lives at lane (lg<<2)+r
    float lm[4];
#pragma unroll
    for (int r = 0; r < 4; ++r) lm[r] = __shfl(l_run, (lg << 2) + r, 64);
#pragma unroll
    for (int r = 0; r < 4; ++r) {
        float inv = lm[r] > 0.f ? 1.0f / lm[r] : 0.f;
        int q = q0 + (lg << 2) + r;
        unsigned short* cp = ctx + ((size_t)(b * S_ + q)) * D_ + h * DH_ + lr;
#pragma unroll
        for (int nb2 = 0; nb2 < 8; ++nb2)
            cp[nb2 * 16] = f32_to_bf16(o[nb2][r] * inv);
    }
#undef STAGE_KV
#undef LOAD_BM
#undef COMPUTE
}

// ---------------------------------------------------------------------------
extern "C" void kernel_launch(void* const* d_in, const int* in_sizes, int n_in,
                              void* d_out, int out_size, void* d_ws, size_t ws_size,
                              hipStream_t stream) {
    const float* hq   = (const float*)d_in[0];
    const float* hkv  = (const float*)d_in[1];
    const void*  mask = d_in[2];
    const float* bias = (const float*)d_in[3];
    const float* Wq   = (const float*)d_in[4];
    const float* Wk   = (const float*)d_in[5];
    const float* Wv   = (const float*)d_in[6];
    const float* Wo   = (const float*)d_in[7];
    float* out = (float*)d_out;

    char* ws = (char*)d_ws;
    unsigned char* mask_c = (unsigned char*)ws;                        // 2 MB
    int* flag             = (int*)(ws + (2u << 20));
    unsigned short* hq_b  = (unsigned short*)(ws + (2u << 20) + 4096); // 16 MB
    unsigned short* hkv_b = hq_b + ((size_t)1 << 23);                  // 16 MB
    unsigned short* WTq   = hkv_b + ((size_t)1 << 23);                 // 32 MB
    unsigned short* WTo   = WTq + ((size_t)1 << 24);                   // 32 MB
    unsigned short* WTkv  = WTo + ((size_t)1 << 24);                   // 64 MB
    unsigned short* Qws   = WTkv + ((size_t)1 << 25);                  // 16 MB
    unsigned short* KVws  = Qws + ((size_t)1 << 23);                   // 32 MB
    unsigned short* Cws   = KVws + ((size_t)1 << 24);                  // 16 MB
    unsigned short* Vtw   = Cws + ((size_t)1 << 23);                   // 16 MB
    float* Pws            = (float*)(Vtw + ((size_t)1 << 23));         // 64 MB

    detect_mask_kernel<<<1, 64, 0, stream>>>((const unsigned char*)mask, flag);
    canon_mask_kernel<<<8192, 256, 0, stream>>>(mask, flag, mask_c, B_ * S_ * S_);
    cvt2_bf16_kernel<<<16384, 256, 0, stream>>>(hq, hkv, hq_b, hkv_b);
    transpose_all_kernel<<<16384, 256, 0, stream>>>(Wq, Wk, Wv, Wo, WTq, WTkv, WTo);

    gemm_qkv_kernel<<<512, 512, 0, stream>>>(hq_b, WTq, Pws, hkv_b, WTkv, KVws);
    reduce_q_kernel<<<(M_ * D_) / 1024, 256, 0, stream>>>(Pws, Qws);

    vt_kernel<<<B_ * H_ * 16 * 2, 256, 0, stream>>>(KVws, Vtw);
    attn_kernel<<<B_ * H_ * (S_ / 64), 256, 0, stream>>>(Qws, KVws, Vtw, bias, mask_c, Cws);

    gemm_o_kernel<<<256, 512, 0, stream>>>(Cws, WTo, Pws);
    reduce_o_kernel<<<(M_ * D_) / 1024, 256, 0, stream>>>(Pws, out);
}

// Round 12
// 500.864 us; speedup vs baseline: 1.0367x; 1.0367x over previous
//
#include <hip/hip_runtime.h>
#include <stdint.h>

// ---------------------------------------------------------------------------
// CPMAntAttention: B=2,S=1024,D=4096,H=32,DH=128
// Round 12: consolidate. attn reverted to r10 (best: dbuf global_load_lds,
// swapped QK^T) + bijective XCD-grouping of same-(b,h) blocks (K/V L2-res).
// transpose_all write side widened to 16B/lane. GEMMs identical to r9/r10.
// ---------------------------------------------------------------------------

#define B_  2
#define S_  1024
#define D_  4096
#define H_  32
#define DH_ 128
#define M_  (B_ * S_)          // 2048
#define KSTR 8192              // row stride of fused KV output

typedef __attribute__((ext_vector_type(8))) short bf16x8;
typedef __attribute__((ext_vector_type(8))) unsigned short u16x8;
typedef __attribute__((ext_vector_type(4))) float f32x4;

static __device__ __forceinline__ unsigned short f32_to_bf16(float f) {
    unsigned int x = __float_as_uint(f);
    x += 0x7fffu + ((x >> 16) & 1u);   // RNE
    return (unsigned short)(x >> 16);
}

static __device__ __forceinline__ f32x4 mfma16(bf16x8 a, bf16x8 b, f32x4 c) {
    return __builtin_amdgcn_mfma_f32_16x16x32_bf16(a, b, c, 0, 0, 0);
}

#if defined(__has_builtin)
#if __has_builtin(__builtin_amdgcn_global_load_lds)
#define HAVE_GLOAD_LDS 1
#endif
#endif

#ifdef HAVE_GLOAD_LDS
#define GLD16(g, lbase, lane)                                                  \
    __builtin_amdgcn_global_load_lds(                                          \
        (const __attribute__((address_space(1))) void*)(g),                    \
        (__attribute__((address_space(3))) void*)(lbase), 16, 0, 0)
#else
#define GLD16(g, lbase, lane)                                                  \
    do { *(bf16x8*)((unsigned short*)(lbase) + (size_t)(lane) * 8) =           \
             *(const bf16x8*)(g); } while (0)
#endif

// ---------------------------------------------------------------------------
__global__ void detect_mask_kernel(const unsigned char* __restrict__ m, int* flag) {
    int l = threadIdx.x;
    uint4 v = ((const uint4*)m)[l];
    unsigned int ww[4] = {v.x, v.y, v.z, v.w};
    int nz_hi = 0, nz_lo01 = 0;
#pragma unroll
    for (int wi = 0; wi < 4; ++wi)
#pragma unroll
        for (int bi = 0; bi < 4; ++bi) {
            unsigned int byte = (ww[wi] >> (bi * 8)) & 0xffu;
            if (byte && bi != 0) nz_hi = 1;
            if (byte && bi <= 1) nz_lo01 = 1;
        }
    int any_hi = __any(nz_hi);
    int any_lo01 = __any(nz_lo01);
    if (l == 0) *flag = (!any_hi) ? 1 : ((!any_lo01) ? 2 : 0);
}

__global__ void canon_mask_kernel(const void* __restrict__ m, const int* __restrict__ flag,
                                  unsigned char* __restrict__ out, int n) {
    int i = blockIdx.x * 256 + threadIdx.x;
    if (i >= n) return;
    int f = *flag;
    unsigned char v;
    if (f == 1)      v = (unsigned char)(((const int*)m)[i] != 0);
    else if (f == 2) v = (unsigned char)(((const float*)m)[i] != 0.0f);
    else             v = (unsigned char)(((const unsigned char*)m)[i] != 0);
    out[i] = v;
}

__global__ void cvt2_bf16_kernel(const float* __restrict__ a, const float* __restrict__ b,
                                 unsigned short* __restrict__ oa, unsigned short* __restrict__ ob) {
    int i = blockIdx.x * 256 + threadIdx.x;
    const int n4 = (B_ * S_ * D_) / 4;
    const float* src = (i < n4) ? a : b;
    unsigned short* dst = (i < n4) ? oa : ob;
    int j = (i < n4) ? i : i - n4;
    float4 v = ((const float4*)src)[j];
    ushort4 o;
    o.x = f32_to_bf16(v.x); o.y = f32_to_bf16(v.y);
    o.z = f32_to_bf16(v.z); o.w = f32_to_bf16(v.w);
    ((ushort4*)dst)[j] = o;
}

// W [4096][4096] fp32 -> WT [n][k] bf16; 64x64 tiles; 16B/lane writes.
__global__ __launch_bounds__(256) void transpose_all_kernel(
        const float* __restrict__ Wq, const float* __restrict__ Wk,
        const float* __restrict__ Wv, const float* __restrict__ Wo,
        unsigned short* __restrict__ WTq, unsigned short* __restrict__ WTkv,
        unsigned short* __restrict__ WTo) {
    __shared__ unsigned short lds[64][65];
    int which = blockIdx.x >> 12;
    int bid = blockIdx.x & 4095;
    const float* W = (which == 0) ? Wq : (which == 1) ? Wk : (which == 2) ? Wv : Wo;
    unsigned short* WT = (which == 0) ? WTq
                       : (which == 1) ? WTkv
                       : (which == 2) ? (WTkv + (size_t)4096 * 4096)
                                      : WTo;
    int bx = bid & 63;    // n tile
    int by = bid >> 6;    // k tile
    int t = threadIdx.x;
    int tr = t >> 4;              // 0..15
    int tc = (t & 15) * 4;        // 0..60
#pragma unroll
    for (int p = 0; p < 4; ++p) {
        int r = p * 16 + tr;
        float4 v = *(const float4*)(W + (size_t)(by * 64 + r) * D_ + bx * 64 + tc);
        lds[r][tc + 0] = f32_to_bf16(v.x);
        lds[r][tc + 1] = f32_to_bf16(v.y);
        lds[r][tc + 2] = f32_to_bf16(v.z);
        lds[r][tc + 3] = f32_to_bf16(v.w);
    }
    __syncthreads();
    // write: n = p2*32 + (t>>3), k-run = (t&7)*8 .. +7  (16B/lane)
    int wn = t >> 3;              // 0..31
    int k0 = (t & 7) * 8;         // 0..56
#pragma unroll
    for (int p2 = 0; p2 < 2; ++p2) {
        int n = p2 * 32 + wn;
        u16x8 o;
#pragma unroll
        for (int j = 0; j < 8; ++j) o[j] = lds[k0 + j][n];
        *(u16x8*)(WT + (size_t)(bx * 64 + n) * D_ + by * 64 + k0) = o;
    }
}

__global__ __launch_bounds__(256) void vt_kernel(const unsigned short* __restrict__ KV,
                                                 unsigned short* __restrict__ Vtw) {
    __shared__ unsigned short lds[64][72];
    int bid = blockIdx.x;
    int dt = bid & 1;
    int st = (bid >> 1) & 15;
    int h  = (bid >> 5) & 31;
    int b  = bid >> 10;
    int t = threadIdx.x;
    int r = t >> 2;
    int c0 = (t & 3) * 16;
    const unsigned short* src =
        KV + (size_t)(b * S_ + st * 64 + r) * KSTR + 4096 + h * DH_ + dt * 64 + c0;
    bf16x8 v0 = *(const bf16x8*)(src);
    bf16x8 v1 = *(const bf16x8*)(src + 8);
    *(bf16x8*)&lds[r][c0] = v0;
    *(bf16x8*)&lds[r][c0 + 8] = v1;
    __syncthreads();
    unsigned short tmp[16];
#pragma unroll
    for (int i = 0; i < 16; ++i) tmp[i] = lds[c0 + i][r];
    unsigned short* dst =
        Vtw + ((size_t)((b * H_ + h) * DH_ + dt * 64 + r)) * S_ + st * 64 + c0;
    *(bf16x8*)dst = *(bf16x8*)&tmp[0];
    *(bf16x8*)(dst + 8) = *(bf16x8*)&tmp[8];
}

// ---------------------------------------------------------------------------
// Phase-pipelined GEMM core (r6, unchanged). Tile 256x256, BK=64, 512 thr.
__device__ __forceinline__ void gemm_core(const unsigned short* __restrict__ A,
                                          const unsigned short* __restrict__ BT,
                                          void* __restrict__ C, int out_f32,
                                          int m0, int n0, int cstride,
                                          int koff, int NT, char* ldsc) {
    const int t = threadIdx.x;
    const int w = t >> 6, l = t & 63;
    const int lr = l & 15, lg = l >> 4;
    const int wmh = w >> 2;
    const int walf = w & 3;
    const int wm = wmh << 7;
    const int wn = walf << 6;

    const int ca0 = lg ^ (lr & 7);
    const int aoff0 = lr * 128 + (ca0 << 4);
    const int aoff1 = lr * 128 + ((ca0 ^ 4) << 4);
    const int boff0 = ((walf & 1) * 64 + lr) * 128 + (ca0 << 4);
    const int boff1 = ((walf & 1) * 64 + lr) * 128 + ((ca0 ^ 4) << 4);

    const int srow = t >> 3;
    const int sch = (t & 7) ^ (srow & 7);
    const size_t soff0 = (size_t)srow * 4096 + (size_t)(sch << 3);
    const size_t soff1 = soff0 + (size_t)64 * 4096;
    const int ldso = w << 10;

    f32x4 ac[8][4];
    f32x4 vzero = {0.f, 0.f, 0.f, 0.f};
#pragma unroll
    for (int i = 0; i < 8; ++i)
#pragma unroll
        for (int j = 0; j < 4; ++j) ac[i][j] = vzero;

#define STAGE_ELEM(E, SS)                                                      \
    do {                                                                       \
        int er_ = (E) & 3;                                                     \
        const unsigned short* mb_ = (er_ < 2)                                  \
            ? A + (size_t)(m0 + ((er_ & 1) << 7)) * 4096                       \
            : BT + (size_t)(n0 + ((er_ & 1) << 7)) * 4096;                     \
        mb_ += (size_t)((((E) >> 2) << 6) + koff);                             \
        char* d0_ = ldsc + (SS) * 16384 + ldso;                                \
        GLD16(mb_ + soff0, d0_, l);                                            \
        GLD16(mb_ + soff1, d0_ + 8192, l);                                     \
    } while (0)

#pragma unroll
    for (int e = 0; e < 5; ++e) STAGE_ELEM(e, e);

    const int NT4 = NT << 2;
    int E = 5, ss = 5, s0 = 0;
    bf16x8 bfr[4][2];

#pragma unroll 1
    for (int tau = 0; tau < NT; ++tau) {
        int sA = s0 + wmh;          if (sA >= 9) sA -= 9;
        int sB = s0 + 2 + (walf >> 1); if (sB >= 9) sB -= 9;
        const char* pA0 = ldsc + sA * 16384 + aoff0;
        const char* pA1 = ldsc + sA * 16384 + aoff1;
        const char* pB0 = ldsc + sB * 16384 + boff0;
        const char* pB1 = ldsc + sB * 16384 + boff1;
#pragma unroll
        for (int r = 0; r < 4; ++r) {
            if (r == 0) {
                if (tau == NT - 1)
                    asm volatile("s_waitcnt vmcnt(0)" ::: "memory");
                else
                    asm volatile("s_waitcnt vmcnt(2)" ::: "memory");
            }
            __builtin_amdgcn_s_barrier();
            asm volatile("" ::: "memory");
            if (r == 0) {
#pragma unroll
                for (int nf = 0; nf < 4; ++nf) {
                    bfr[nf][0] = *(const bf16x8*)(pB0 + nf * 2048);
                    bfr[nf][1] = *(const bf16x8*)(pB1 + nf * 2048);
                }
            }
            bf16x8 af[2][2];
            int mfb = r << 1;
#pragma unroll
            for (int j = 0; j < 2; ++j) {
                af[j][0] = *(const bf16x8*)(pA0 + (mfb + j) * 2048);
                af[j][1] = *(const bf16x8*)(pA1 + (mfb + j) * 2048);
            }
            if (E < NT4) STAGE_ELEM(E, ss);
            ++E; ss = (ss == 8) ? 0 : ss + 1;
            __builtin_amdgcn_s_setprio(1);
#pragma unroll
            for (int j = 0; j < 2; ++j)
#pragma unroll
                for (int nf = 0; nf < 4; ++nf) {
                    ac[mfb + j][nf] = mfma16(af[j][0], bfr[nf][0], ac[mfb + j][nf]);
                    ac[mfb + j][nf] = mfma16(af[j][1], bfr[nf][1], ac[mfb + j][nf]);
                }
            __builtin_amdgcn_s_setprio(0);
        }
        s0 += 4; if (s0 >= 9) s0 -= 9;
    }
#undef STAGE_ELEM

#pragma unroll
    for (int mf = 0; mf < 8; ++mf)
#pragma unroll
        for (int nf = 0; nf < 4; ++nf)
#pragma unroll
            for (int q = 0; q < 4; ++q) {
                int row = m0 + wm + mf * 16 + lg * 4 + q;
                int col = n0 + wn + nf * 16 + lr;
                if (out_f32)
                    ((float*)C)[(size_t)row * cstride + col] = ac[mf][nf][q];
                else
                    ((unsigned short*)C)[(size_t)row * cstride + col] = f32_to_bf16(ac[mf][nf][q]);
            }
}

// 512 blocks, two homogeneous rounds (r9): 0..255 KV full-K, 256..511 Q splitK2.
__global__ __launch_bounds__(512, 2) void gemm_qkv_kernel(
        const unsigned short* __restrict__ Aq, const unsigned short* __restrict__ Bq,
        float* __restrict__ Pq,
        const unsigned short* __restrict__ Akv, const unsigned short* __restrict__ Bkv,
        unsigned short* __restrict__ Ckv) {
    __shared__ char ldsbuf[9 * 16384];
    int bid = blockIdx.x;
    if (bid < 256) {
        int bm = bid & 7, bn = bid >> 3;
        gemm_core(Akv, Bkv, Ckv, 0, bm << 8, bn << 8, 8192, 0, 64, ldsbuf);
    } else {
        int e = bid - 256;
        int bm = e & 7;
        int rest = e >> 3;
        int bn = rest & 15;
        int ks = rest >> 4;
        gemm_core(Aq, Bq, Pq + (size_t)ks * M_ * D_, 1, bm << 8, bn << 8, 4096,
                  ks * 2048, 32, ldsbuf);
    }
}

__global__ void reduce_q_kernel(const float* __restrict__ P, unsigned short* __restrict__ out) {
    int i = blockIdx.x * 256 + threadIdx.x;
    float4 a = ((const float4*)P)[i];
    float4 b = ((const float4*)(P + (size_t)M_ * D_))[i];
    ushort4 o;
    o.x = f32_to_bf16(a.x + b.x); o.y = f32_to_bf16(a.y + b.y);
    o.z = f32_to_bf16(a.z + b.z); o.w = f32_to_bf16(a.w + b.w);
    ((ushort4*)out)[i] = o;
}

__global__ __launch_bounds__(512, 2) void gemm_o_kernel(
        const unsigned short* __restrict__ A, const unsigned short* __restrict__ BT,
        float* __restrict__ P) {
    __shared__ char ldsbuf[9 * 16384];
    int bid = blockIdx.x;
    int bm = bid & 7;
    int rest = bid >> 3;
    int bn = rest & 15;
    int ks = rest >> 4;
    gemm_core(A, BT, P + (size_t)ks * M_ * D_, 1, bm << 8, bn << 8, 4096,
              ks * 2048, 32, ldsbuf);
}

__global__ void reduce_o_kernel(const float* __restrict__ P, float* __restrict__ out) {
    int i = blockIdx.x * 256 + threadIdx.x;
    float4 a = ((const float4*)P)[i];
    float4 b = ((const float4*)(P + (size_t)M_ * D_))[i];
    float4 o; o.x = a.x + b.x; o.y = a.y + b.y; o.z = a.z + b.z; o.w = a.w + b.w;
    ((float4*)out)[i] = o;
}

// ---------------------------------------------------------------------------
// Flash attention (r10, proven best): dbuf global_load_lds K/V, swapped QK^T,
// wide bias/mask loads, lane-local softmax. XCD-grouped block remap: all 16
// q-tiles of one (b,h) land on one XCD -> that head's K/V stays L2-resident.
#define NEGF (-1e30f)
__global__ __launch_bounds__(256, 2) void attn_kernel(const unsigned short* __restrict__ Qw,
                                                      const unsigned short* __restrict__ KV,
                                                      const unsigned short* __restrict__ Vtw,
                                                      const float* __restrict__ bias,
                                                      const unsigned char* __restrict__ maskc,
                                                      unsigned short* __restrict__ ctx) {
    __shared__ unsigned short Kbuf[2][64 * 128];
    __shared__ unsigned short Vbuf[2][128 * 64];
    __shared__ unsigned short Plds[4][16 * 72];

    // bijective remap: xcd = x&7 fixed per group g = gq*8+xcd (dispatch uses
    // bid%8 -> XCD round-robin), qt enumerates within group.
    int x = blockIdx.x;
    int xcd = x & 7;
    int rest = x >> 3;           // 0..127
    int qt = rest & 15;
    int gq = rest >> 4;          // 0..7
    int g = gq * 8 + xcd;        // 0..63
    int b = g >> 5, h = g & 31;

    int t = threadIdx.x, w = t >> 6, l = t & 63;
    int lr = l & 15, lg = l >> 4;
    int q0 = (qt << 6) + (w << 4);

    bf16x8 qf[4];
    const unsigned short* Qp = Qw + ((size_t)(b * S_ + q0 + lr)) * D_ + h * DH_ + lg * 8;
#pragma unroll
    for (int kf = 0; kf < 4; ++kf) qf[kf] = *(const bf16x8*)(Qp + kf * 32);

    f32x4 o[8];
    f32x4 vzero = {0.f, 0.f, 0.f, 0.f};
#pragma unroll
    for (int i = 0; i < 8; ++i) o[i] = vzero;
    float m_run = NEGF, l_run = 0.f;     // per-lane: q-row = q0 + lr

    const float* biasp = bias + (((size_t)(b * H_ + h)) << 20)
                              + (((size_t)(q0 + lr)) << 10);
    const unsigned char* mp = maskc + ((size_t)b << 20)
                              + (((size_t)(q0 + lr)) << 10);
    const unsigned short* Kg = KV + (size_t)(b * S_) * KSTR + h * DH_;
    const unsigned short* Vg = Vtw + (((size_t)(b * H_ + h)) * DH_) * S_;

    float4 br0[4], br1[4];
    unsigned int mr0[4], mr1[4];

#define STAGE_KV(KT, BUF)                                                          \
    do { int kv0_ = (KT) << 6;                                                     \
        _Pragma("unroll")                                                          \
        for (int c = 0; c < 4; ++c) {                                              \
            int seg = (w << 2) + c;                                                \
            int krow = (seg << 2) + (l >> 4);                                      \
            int kch = (l & 15) ^ (krow & 7);                                       \
            GLD16(Kg + (size_t)(kv0_ + krow) * KSTR + (kch << 3),                  \
                  &Kbuf[BUF][seg << 9], l);                                        \
            int vrow = (seg << 3) + (l >> 3);                                      \
            int vch = (l & 7) ^ (vrow & 7);                                        \
            GLD16(Vg + (size_t)vrow * S_ + kv0_ + (vch << 3),                      \
                  &Vbuf[BUF][seg << 9], l);                                        \
        }                                                                          \
    } while (0)

#define LOAD_BM(BR, MR, KT)                                                        \
    do { int kv0_ = (KT) << 6;                                                     \
        _Pragma("unroll")                                                          \
        for (int nb = 0; nb < 4; ++nb) {                                           \
            BR[nb] = *(const float4*)(biasp + kv0_ + (nb << 4) + (lg << 2));       \
            MR[nb] = *(const unsigned int*)(mp + kv0_ + (nb << 4) + (lg << 2));    \
        }                                                                          \
    } while (0)

#define COMPUTE(BUF, BR, MR)                                                       \
    do {                                                                           \
        f32x4 s_[4];                                                               \
        __builtin_amdgcn_s_setprio(1);                                             \
        _Pragma("unroll")                                                          \
        for (int nb = 0; nb < 4; ++nb) {                                           \
            s_[nb] = vzero;                                                        \
            int krow = (nb << 4) + lr;                                             \
            _Pragma("unroll")                                                      \
            for (int kf = 0; kf < 4; ++kf) {                                       \
                int ba = ((krow << 8) + (((kf << 5) + (lg << 3)) << 1))            \
                         ^ ((krow & 7) << 4);                                      \
                bf16x8 kfr = *(const bf16x8*)((const char*)Kbuf[BUF] + ba);        \
                s_[nb] = mfma16(kfr, qf[kf], s_[nb]);                              \
            }                                                                      \
        }                                                                          \
        __builtin_amdgcn_s_setprio(0);                                             \
        float sv[4][4];                                                            \
        _Pragma("unroll")                                                          \
        for (int nb = 0; nb < 4; ++nb) {                                           \
            float bb[4] = {BR[nb].x, BR[nb].y, BR[nb].z, BR[nb].w};                \
            _Pragma("unroll")                                                      \
            for (int r = 0; r < 4; ++r) {                                          \
                float x2 = fmaf(s_[nb][r], 0.08838834764831845f, bb[r]);           \
                sv[nb][r] = ((MR[nb] >> (r * 8)) & 0xffu) ? x2 : NEGF;             \
            }                                                                      \
        }                                                                          \
        float mt = sv[0][0];                                                       \
        _Pragma("unroll")                                                          \
        for (int nb = 0; nb < 4; ++nb)                                             \
            _Pragma("unroll")                                                      \
            for (int r = 0; r < 4; ++r) mt = fmaxf(mt, sv[nb][r]);                 \
        mt = fmaxf(mt, __shfl_xor(mt, 16, 64));                                    \
        mt = fmaxf(mt, __shfl_xor(mt, 32, 64));                                    \
        float mn = fmaxf(m_run, mt);                                               \
        float al = __expf(m_run - mn);                                             \
        m_run = mn;                                                                \
        float rs = 0.f;                                                            \
        _Pragma("unroll")                                                          \
        for (int nb = 0; nb < 4; ++nb)                                             \
            _Pragma("unroll")                                                      \
            for (int r = 0; r < 4; ++r) {                                          \
                sv[nb][r] = __expf(sv[nb][r] - m_run);                             \
                rs += sv[nb][r];                                                   \
            }                                                                      \
        rs += __shfl_xor(rs, 16, 64);                                              \
        rs += __shfl_xor(rs, 32, 64);                                              \
        l_run = l_run * al + rs;                                                   \
        float alm[4];                                                              \
        _Pragma("unroll")                                                          \
        for (int r = 0; r < 4; ++r) alm[r] = __shfl(al, (lg << 2) + r, 64);        \
        _Pragma("unroll")                                                          \
        for (int nb2 = 0; nb2 < 8; ++nb2) {                                        \
            o[nb2][0] *= alm[0]; o[nb2][1] *= alm[1];                              \
            o[nb2][2] *= alm[2]; o[nb2][3] *= alm[3];                              \
        }                                                                          \
        _Pragma("unroll")                                                          \
        for (int nb = 0; nb < 4; ++nb)                                             \
            _Pragma("unroll")                                                      \
            for (int r = 0; r < 4; ++r)                                            \
                Plds[w][lr * 72 + (nb << 4) + (lg << 2) + r] = f32_to_bf16(sv[nb][r]); \
        __builtin_amdgcn_s_setprio(1);                                             \
        _Pragma("unroll")                                                          \
        for (int kf2 = 0; kf2 < 2; ++kf2) {                                        \
            bf16x8 pf = *(const bf16x8*)&Plds[w][lr * 72 + (kf2 << 5) + (lg << 3)]; \
            _Pragma("unroll")                                                      \
            for (int nb2 = 0; nb2 < 8; ++nb2) {                                    \
                int dh = (nb2 << 4) + lr;                                          \
                int ba = ((dh << 7) + (((kf2 << 5) + (lg << 3)) << 1))             \
                         ^ ((dh & 7) << 4);                                        \
                bf16x8 vf = *(const bf16x8*)((const char*)Vbuf[BUF] + ba);         \
                o[nb2] = mfma16(pf, vf, o[nb2]);                                   \
            }                                                                      \
        }                                                                          \
        __builtin_amdgcn_s_setprio(0);                                             \
    } while (0)

    STAGE_KV(0, 0);
    LOAD_BM(br0, mr0, 0);

#pragma unroll 1
    for (int kt = 0; kt < 16; kt += 2) {
        __syncthreads();
        STAGE_KV(kt + 1, 1);
        LOAD_BM(br1, mr1, kt + 1);
        COMPUTE(0, br0, mr0);
        __syncthreads();
        if (kt < 14) {
            STAGE_KV(kt + 2, 0);
            LOAD_BM(br0, mr0, kt + 2);
        }
        COMPUTE(1, br1, mr1);
    }

    float lm[4];
#pragma unroll
    for (int r = 0; r < 4; ++r) lm[r] = __shfl(l_run, (lg << 2) + r, 64);
#pragma unroll
    for (int r = 0; r < 4; ++r) {
        float inv = lm[r] > 0.f ? 1.0f / lm[r] : 0.f;
        int q = q0 + (lg << 2) + r;
        unsigned short* cp = ctx + ((size_t)(b * S_ + q)) * D_ + h * DH_ + lr;
#pragma unroll
        for (int nb2 = 0; nb2 < 8; ++nb2)
            cp[nb2 * 16] = f32_to_bf16(o[nb2][r] * inv);
    }
#undef STAGE_KV
#undef LOAD_BM
#undef COMPUTE
}

// ---------------------------------------------------------------------------
extern "C" void kernel_launch(void* const* d_in, const int* in_sizes, int n_in,
                              void* d_out, int out_size, void* d_ws, size_t ws_size,
                              hipStream_t stream) {
    const float* hq   = (const float*)d_in[0];
    const float* hkv  = (const float*)d_in[1];
    const void*  mask = d_in[2];
    const float* bias = (const float*)d_in[3];
    const float* Wq   = (const float*)d_in[4];
    const float* Wk   = (const float*)d_in[5];
    const float* Wv   = (const float*)d_in[6];
    const float* Wo   = (const float*)d_in[7];
    float* out = (float*)d_out;

    char* ws = (char*)d_ws;
    unsigned char* mask_c = (unsigned char*)ws;                        // 2 MB
    int* flag             = (int*)(ws + (2u << 20));
    unsigned short* hq_b  = (unsigned short*)(ws + (2u << 20) + 4096); // 16 MB
    unsigned short* hkv_b = hq_b + ((size_t)1 << 23);                  // 16 MB
    unsigned short* WTq   = hkv_b + ((size_t)1 << 23);                 // 32 MB
    unsigned short* WTo   = WTq + ((size_t)1 << 24);                   // 32 MB
    unsigned short* WTkv  = WTo + ((size_t)1 << 24);                   // 64 MB
    unsigned short* Qws   = WTkv + ((size_t)1 << 25);                  // 16 MB
    unsigned short* KVws  = Qws + ((size_t)1 << 23);                   // 32 MB
    unsigned short* Cws   = KVws + ((size_t)1 << 24);                  // 16 MB
    unsigned short* Vtw   = Cws + ((size_t)1 << 23);                   // 16 MB
    float* Pws            = (float*)(Vtw + ((size_t)1 << 23));         // 64 MB

    detect_mask_kernel<<<1, 64, 0, stream>>>((const unsigned char*)mask, flag);
    canon_mask_kernel<<<8192, 256, 0, stream>>>(mask, flag, mask_c, B_ * S_ * S_);
    cvt2_bf16_kernel<<<16384, 256, 0, stream>>>(hq, hkv, hq_b, hkv_b);
    transpose_all_kernel<<<16384, 256, 0, stream>>>(Wq, Wk, Wv, Wo, WTq, WTkv, WTo);

    gemm_qkv_kernel<<<512, 512, 0, stream>>>(hq_b, WTq, Pws, hkv_b, WTkv, KVws);
    reduce_q_kernel<<<(M_ * D_) / 1024, 256, 0, stream>>>(Pws, Qws);

    vt_kernel<<<B_ * H_ * 16 * 2, 256, 0, stream>>>(KVws, Vtw);
    attn_kernel<<<B_ * H_ * (S_ / 64), 256, 0, stream>>>(Qws, KVws, Vtw, bias, mask_c, Cws);

    gemm_o_kernel<<<256, 512, 0, stream>>>(Cws, WTo, Pws);
    reduce_o_kernel<<<(M_ * D_) / 1024, 256, 0, stream>>>(Pws, out);
}

// Round 13
// 499.955 us; speedup vs baseline: 1.0386x; 1.0018x over previous
//
#include <hip/hip_runtime.h>
#include <stdint.h>

// ---------------------------------------------------------------------------
// CPMAntAttention: B=2,S=1024,D=4096,H=32,DH=128
// Round 13: deepen GEMM pipeline. r12's vmcnt(2) forced elem 4t+3 (issued 2
// phases earlier) to land at each tile boundary -> residual stall (MfmaUtil
// 48%). Now: 10 LDS slots (160 KiB exactly), prefetch distance 6, steady
// vmcnt(4), final-tile vmcnt(0). Slot algebra: write offsets {6..9} mod 10
// vs read set {0..3} -> disjoint. Everything else identical to r12.
// ---------------------------------------------------------------------------

#define B_  2
#define S_  1024
#define D_  4096
#define H_  32
#define DH_ 128
#define M_  (B_ * S_)          // 2048
#define KSTR 8192              // row stride of fused KV output

typedef __attribute__((ext_vector_type(8))) short bf16x8;
typedef __attribute__((ext_vector_type(8))) unsigned short u16x8;
typedef __attribute__((ext_vector_type(4))) float f32x4;

static __device__ __forceinline__ unsigned short f32_to_bf16(float f) {
    unsigned int x = __float_as_uint(f);
    x += 0x7fffu + ((x >> 16) & 1u);   // RNE
    return (unsigned short)(x >> 16);
}

static __device__ __forceinline__ f32x4 mfma16(bf16x8 a, bf16x8 b, f32x4 c) {
    return __builtin_amdgcn_mfma_f32_16x16x32_bf16(a, b, c, 0, 0, 0);
}

#if defined(__has_builtin)
#if __has_builtin(__builtin_amdgcn_global_load_lds)
#define HAVE_GLOAD_LDS 1
#endif
#endif

#ifdef HAVE_GLOAD_LDS
#define GLD16(g, lbase, lane)                                                  \
    __builtin_amdgcn_global_load_lds(                                          \
        (const __attribute__((address_space(1))) void*)(g),                    \
        (__attribute__((address_space(3))) void*)(lbase), 16, 0, 0)
#else
#define GLD16(g, lbase, lane)                                                  \
    do { *(bf16x8*)((unsigned short*)(lbase) + (size_t)(lane) * 8) =           \
             *(const bf16x8*)(g); } while (0)
#endif

// ---------------------------------------------------------------------------
__global__ void detect_mask_kernel(const unsigned char* __restrict__ m, int* flag) {
    int l = threadIdx.x;
    uint4 v = ((const uint4*)m)[l];
    unsigned int ww[4] = {v.x, v.y, v.z, v.w};
    int nz_hi = 0, nz_lo01 = 0;
#pragma unroll
    for (int wi = 0; wi < 4; ++wi)
#pragma unroll
        for (int bi = 0; bi < 4; ++bi) {
            unsigned int byte = (ww[wi] >> (bi * 8)) & 0xffu;
            if (byte && bi != 0) nz_hi = 1;
            if (byte && bi <= 1) nz_lo01 = 1;
        }
    int any_hi = __any(nz_hi);
    int any_lo01 = __any(nz_lo01);
    if (l == 0) *flag = (!any_hi) ? 1 : ((!any_lo01) ? 2 : 0);
}

__global__ void canon_mask_kernel(const void* __restrict__ m, const int* __restrict__ flag,
                                  unsigned char* __restrict__ out, int n) {
    int i = blockIdx.x * 256 + threadIdx.x;
    if (i >= n) return;
    int f = *flag;
    unsigned char v;
    if (f == 1)      v = (unsigned char)(((const int*)m)[i] != 0);
    else if (f == 2) v = (unsigned char)(((const float*)m)[i] != 0.0f);
    else             v = (unsigned char)(((const unsigned char*)m)[i] != 0);
    out[i] = v;
}

__global__ void cvt2_bf16_kernel(const float* __restrict__ a, const float* __restrict__ b,
                                 unsigned short* __restrict__ oa, unsigned short* __restrict__ ob) {
    int i = blockIdx.x * 256 + threadIdx.x;
    const int n4 = (B_ * S_ * D_) / 4;
    const float* src = (i < n4) ? a : b;
    unsigned short* dst = (i < n4) ? oa : ob;
    int j = (i < n4) ? i : i - n4;
    float4 v = ((const float4*)src)[j];
    ushort4 o;
    o.x = f32_to_bf16(v.x); o.y = f32_to_bf16(v.y);
    o.z = f32_to_bf16(v.z); o.w = f32_to_bf16(v.w);
    ((ushort4*)dst)[j] = o;
}

// W [4096][4096] fp32 -> WT [n][k] bf16; 64x64 tiles; 16B/lane writes.
__global__ __launch_bounds__(256) void transpose_all_kernel(
        const float* __restrict__ Wq, const float* __restrict__ Wk,
        const float* __restrict__ Wv, const float* __restrict__ Wo,
        unsigned short* __restrict__ WTq, unsigned short* __restrict__ WTkv,
        unsigned short* __restrict__ WTo) {
    __shared__ unsigned short lds[64][65];
    int which = blockIdx.x >> 12;
    int bid = blockIdx.x & 4095;
    const float* W = (which == 0) ? Wq : (which == 1) ? Wk : (which == 2) ? Wv : Wo;
    unsigned short* WT = (which == 0) ? WTq
                       : (which == 1) ? WTkv
                       : (which == 2) ? (WTkv + (size_t)4096 * 4096)
                                      : WTo;
    int bx = bid & 63;    // n tile
    int by = bid >> 6;    // k tile
    int t = threadIdx.x;
    int tr = t >> 4;
    int tc = (t & 15) * 4;
#pragma unroll
    for (int p = 0; p < 4; ++p) {
        int r = p * 16 + tr;
        float4 v = *(const float4*)(W + (size_t)(by * 64 + r) * D_ + bx * 64 + tc);
        lds[r][tc + 0] = f32_to_bf16(v.x);
        lds[r][tc + 1] = f32_to_bf16(v.y);
        lds[r][tc + 2] = f32_to_bf16(v.z);
        lds[r][tc + 3] = f32_to_bf16(v.w);
    }
    __syncthreads();
    int wn = t >> 3;              // 0..31
    int k0 = (t & 7) * 8;         // 0..56
#pragma unroll
    for (int p2 = 0; p2 < 2; ++p2) {
        int n = p2 * 32 + wn;
        u16x8 o;
#pragma unroll
        for (int j = 0; j < 8; ++j) o[j] = lds[k0 + j][n];
        *(u16x8*)(WT + (size_t)(bx * 64 + n) * D_ + by * 64 + k0) = o;
    }
}

__global__ __launch_bounds__(256) void vt_kernel(const unsigned short* __restrict__ KV,
                                                 unsigned short* __restrict__ Vtw) {
    __shared__ unsigned short lds[64][72];
    int bid = blockIdx.x;
    int dt = bid & 1;
    int st = (bid >> 1) & 15;
    int h  = (bid >> 5) & 31;
    int b  = bid >> 10;
    int t = threadIdx.x;
    int r = t >> 2;
    int c0 = (t & 3) * 16;
    const unsigned short* src =
        KV + (size_t)(b * S_ + st * 64 + r) * KSTR + 4096 + h * DH_ + dt * 64 + c0;
    bf16x8 v0 = *(const bf16x8*)(src);
    bf16x8 v1 = *(const bf16x8*)(src + 8);
    *(bf16x8*)&lds[r][c0] = v0;
    *(bf16x8*)&lds[r][c0 + 8] = v1;
    __syncthreads();
    unsigned short tmp[16];
#pragma unroll
    for (int i = 0; i < 16; ++i) tmp[i] = lds[c0 + i][r];
    unsigned short* dst =
        Vtw + ((size_t)((b * H_ + h) * DH_ + dt * 64 + r)) * S_ + st * 64 + c0;
    *(bf16x8*)dst = *(bf16x8*)&tmp[0];
    *(bf16x8*)(dst + 8) = *(bf16x8*)&tmp[8];
}

// ---------------------------------------------------------------------------
// Phase-pipelined GEMM core, r13: 10-slot ring (160 KiB), prefetch dist 6,
// vmcnt(4) steady / vmcnt(0) final tile. Tile 256x256, BK=64, 512 thr.
__device__ __forceinline__ void gemm_core(const unsigned short* __restrict__ A,
                                          const unsigned short* __restrict__ BT,
                                          void* __restrict__ C, int out_f32,
                                          int m0, int n0, int cstride,
                                          int koff, int NT, char* ldsc) {
    const int t = threadIdx.x;
    const int w = t >> 6, l = t & 63;
    const int lr = l & 15, lg = l >> 4;
    const int wmh = w >> 2;
    const int walf = w & 3;
    const int wm = wmh << 7;
    const int wn = walf << 6;

    const int ca0 = lg ^ (lr & 7);
    const int aoff0 = lr * 128 + (ca0 << 4);
    const int aoff1 = lr * 128 + ((ca0 ^ 4) << 4);
    const int boff0 = ((walf & 1) * 64 + lr) * 128 + (ca0 << 4);
    const int boff1 = ((walf & 1) * 64 + lr) * 128 + ((ca0 ^ 4) << 4);

    const int srow = t >> 3;
    const int sch = (t & 7) ^ (srow & 7);
    const size_t soff0 = (size_t)srow * 4096 + (size_t)(sch << 3);
    const size_t soff1 = soff0 + (size_t)64 * 4096;
    const int ldso = w << 10;

    f32x4 ac[8][4];
    f32x4 vzero = {0.f, 0.f, 0.f, 0.f};
#pragma unroll
    for (int i = 0; i < 8; ++i)
#pragma unroll
        for (int j = 0; j < 4; ++j) ac[i][j] = vzero;

#define STAGE_ELEM(E, SS)                                                      \
    do {                                                                       \
        int er_ = (E) & 3;                                                     \
        const unsigned short* mb_ = (er_ < 2)                                  \
            ? A + (size_t)(m0 + ((er_ & 1) << 7)) * 4096                       \
            : BT + (size_t)(n0 + ((er_ & 1) << 7)) * 4096;                     \
        mb_ += (size_t)((((E) >> 2) << 6) + koff);                             \
        char* d0_ = ldsc + (SS) * 16384 + ldso;                                \
        GLD16(mb_ + soff0, d0_, l);                                            \
        GLD16(mb_ + soff1, d0_ + 8192, l);                                     \
    } while (0)

    // prologue: elems 0..5 in flight (12 loads/thread), slots 0..5
#pragma unroll
    for (int e = 0; e < 6; ++e) STAGE_ELEM(e, e);

    const int NT4 = NT << 2;
    int E = 6, ss = 6, s0 = 0;
    bf16x8 bfr[4][2];

#pragma unroll 1
    for (int tau = 0; tau < NT; ++tau) {
        int sA = s0 + wmh;             if (sA >= 10) sA -= 10;
        int sB = s0 + 2 + (walf >> 1); if (sB >= 10) sB -= 10;
        const char* pA0 = ldsc + sA * 16384 + aoff0;
        const char* pA1 = ldsc + sA * 16384 + aoff1;
        const char* pB0 = ldsc + sB * 16384 + boff0;
        const char* pB1 = ldsc + sB * 16384 + boff1;
#pragma unroll
        for (int r = 0; r < 4; ++r) {
            if (r == 0) {
                if (tau == NT - 1)
                    asm volatile("s_waitcnt vmcnt(0)" ::: "memory");
                else
                    asm volatile("s_waitcnt vmcnt(4)" ::: "memory");
            }
            __builtin_amdgcn_s_barrier();
            asm volatile("" ::: "memory");
            if (r == 0) {
#pragma unroll
                for (int nf = 0; nf < 4; ++nf) {
                    bfr[nf][0] = *(const bf16x8*)(pB0 + nf * 2048);
                    bfr[nf][1] = *(const bf16x8*)(pB1 + nf * 2048);
                }
            }
            bf16x8 af[2][2];
            int mfb = r << 1;
#pragma unroll
            for (int j = 0; j < 2; ++j) {
                af[j][0] = *(const bf16x8*)(pA0 + (mfb + j) * 2048);
                af[j][1] = *(const bf16x8*)(pA1 + (mfb + j) * 2048);
            }
            if (E < NT4) STAGE_ELEM(E, ss);
            ++E; ss = (ss == 9) ? 0 : ss + 1;
            __builtin_amdgcn_s_setprio(1);
#pragma unroll
            for (int j = 0; j < 2; ++j)
#pragma unroll
                for (int nf = 0; nf < 4; ++nf) {
                    ac[mfb + j][nf] = mfma16(af[j][0], bfr[nf][0], ac[mfb + j][nf]);
                    ac[mfb + j][nf] = mfma16(af[j][1], bfr[nf][1], ac[mfb + j][nf]);
                }
            __builtin_amdgcn_s_setprio(0);
        }
        s0 += 4; if (s0 >= 10) s0 -= 10;
    }
#undef STAGE_ELEM

#pragma unroll
    for (int mf = 0; mf < 8; ++mf)
#pragma unroll
        for (int nf = 0; nf < 4; ++nf)
#pragma unroll
            for (int q = 0; q < 4; ++q) {
                int row = m0 + wm + mf * 16 + lg * 4 + q;
                int col = n0 + wn + nf * 16 + lr;
                if (out_f32)
                    ((float*)C)[(size_t)row * cstride + col] = ac[mf][nf][q];
                else
                    ((unsigned short*)C)[(size_t)row * cstride + col] = f32_to_bf16(ac[mf][nf][q]);
            }
}

// 512 blocks, two homogeneous rounds (r9): 0..255 KV full-K, 256..511 Q splitK2.
__global__ __launch_bounds__(512, 1) void gemm_qkv_kernel(
        const unsigned short* __restrict__ Aq, const unsigned short* __restrict__ Bq,
        float* __restrict__ Pq,
        const unsigned short* __restrict__ Akv, const unsigned short* __restrict__ Bkv,
        unsigned short* __restrict__ Ckv) {
    __shared__ char ldsbuf[10 * 16384];   // 160 KiB exactly
    int bid = blockIdx.x;
    if (bid < 256) {
        int bm = bid & 7, bn = bid >> 3;
        gemm_core(Akv, Bkv, Ckv, 0, bm << 8, bn << 8, 8192, 0, 64, ldsbuf);
    } else {
        int e = bid - 256;
        int bm = e & 7;
        int rest = e >> 3;
        int bn = rest & 15;
        int ks = rest >> 4;
        gemm_core(Aq, Bq, Pq + (size_t)ks * M_ * D_, 1, bm << 8, bn << 8, 4096,
                  ks * 2048, 32, ldsbuf);
    }
}

__global__ void reduce_q_kernel(const float* __restrict__ P, unsigned short* __restrict__ out) {
    int i = blockIdx.x * 256 + threadIdx.x;
    float4 a = ((const float4*)P)[i];
    float4 b = ((const float4*)(P + (size_t)M_ * D_))[i];
    ushort4 o;
    o.x = f32_to_bf16(a.x + b.x); o.y = f32_to_bf16(a.y + b.y);
    o.z = f32_to_bf16(a.z + b.z); o.w = f32_to_bf16(a.w + b.w);
    ((ushort4*)out)[i] = o;
}

__global__ __launch_bounds__(512, 1) void gemm_o_kernel(
        const unsigned short* __restrict__ A, const unsigned short* __restrict__ BT,
        float* __restrict__ P) {
    __shared__ char ldsbuf[10 * 16384];   // 160 KiB exactly
    int bid = blockIdx.x;
    int bm = bid & 7;
    int rest = bid >> 3;
    int bn = rest & 15;
    int ks = rest >> 4;
    gemm_core(A, BT, P + (size_t)ks * M_ * D_, 1, bm << 8, bn << 8, 4096,
              ks * 2048, 32, ldsbuf);
}

__global__ void reduce_o_kernel(const float* __restrict__ P, float* __restrict__ out) {
    int i = blockIdx.x * 256 + threadIdx.x;
    float4 a = ((const float4*)P)[i];
    float4 b = ((const float4*)(P + (size_t)M_ * D_))[i];
    float4 o; o.x = a.x + b.x; o.y = a.y + b.y; o.z = a.z + b.z; o.w = a.w + b.w;
    ((float4*)out)[i] = o;
}

// ---------------------------------------------------------------------------
// Flash attention (r12 best): dbuf global_load_lds K/V, swapped QK^T, wide
// bias/mask loads, lane-local softmax, XCD-grouped block remap.
#define NEGF (-1e30f)
__global__ __launch_bounds__(256, 2) void attn_kernel(const unsigned short* __restrict__ Qw,
                                                      const unsigned short* __restrict__ KV,
                                                      const unsigned short* __restrict__ Vtw,
                                                      const float* __restrict__ bias,
                                                      const unsigned char* __restrict__ maskc,
                                                      unsigned short* __restrict__ ctx) {
    __shared__ unsigned short Kbuf[2][64 * 128];
    __shared__ unsigned short Vbuf[2][128 * 64];
    __shared__ unsigned short Plds[4][16 * 72];

    int x = blockIdx.x;
    int xcd = x & 7;
    int rest = x >> 3;           // 0..127
    int qt = rest & 15;
    int gq = rest >> 4;          // 0..7
    int g = gq * 8 + xcd;        // 0..63
    int b = g >> 5, h = g & 31;

    int t = threadIdx.x, w = t >> 6, l = t & 63;
    int lr = l & 15, lg = l >> 4;
    int q0 = (qt << 6) + (w << 4);

    bf16x8 qf[4];
    const unsigned short* Qp = Qw + ((size_t)(b * S_ + q0 + lr)) * D_ + h * DH_ + lg * 8;
#pragma unroll
    for (int kf = 0; kf < 4; ++kf) qf[kf] = *(const bf16x8*)(Qp + kf * 32);

    f32x4 o[8];
    f32x4 vzero = {0.f, 0.f, 0.f, 0.f};
#pragma unroll
    for (int i = 0; i < 8; ++i) o[i] = vzero;
    float m_run = NEGF, l_run = 0.f;     // per-lane: q-row = q0 + lr

    const float* biasp = bias + (((size_t)(b * H_ + h)) << 20)
                              + (((size_t)(q0 + lr)) << 10);
    const unsigned char* mp = maskc + ((size_t)b << 20)
                              + (((size_t)(q0 + lr)) << 10);
    const unsigned short* Kg = KV + (size_t)(b * S_) * KSTR + h * DH_;
    const unsigned short* Vg = Vtw + (((size_t)(b * H_ + h)) * DH_) * S_;

    float4 br0[4], br1[4];
    unsigned int mr0[4], mr1[4];

#define STAGE_KV(KT, BUF)                                                          \
    do { int kv0_ = (KT) << 6;                                                     \
        _Pragma("unroll")                                                          \
        for (int c = 0; c < 4; ++c) {                                              \
            int seg = (w << 2) + c;                                                \
            int krow = (seg << 2) + (l >> 4);                                      \
            int kch = (l & 15) ^ (krow & 7);                                       \
            GLD16(Kg + (size_t)(kv0_ + krow) * KSTR + (kch << 3),                  \
                  &Kbuf[BUF][seg << 9], l);                                        \
            int vrow = (seg << 3) + (l >> 3);                                      \
            int vch = (l & 7) ^ (vrow & 7);                                        \
            GLD16(Vg + (size_t)vrow * S_ + kv0_ + (vch << 3),                      \
                  &Vbuf[BUF][seg << 9], l);                                        \
        }                                                                          \
    } while (0)

#define LOAD_BM(BR, MR, KT)                                                        \
    do { int kv0_ = (KT) << 6;                                                     \
        _Pragma("unroll")                                                          \
        for (int nb = 0; nb < 4; ++nb) {                                           \
            BR[nb] = *(const float4*)(biasp + kv0_ + (nb << 4) + (lg << 2));       \
            MR[nb] = *(const unsigned int*)(mp + kv0_ + (nb << 4) + (lg << 2));    \
        }                                                                          \
    } while (0)

#define COMPUTE(BUF, BR, MR)                                                       \
    do {                                                                           \
        f32x4 s_[4];                                                               \
        __builtin_amdgcn_s_setprio(1);                                             \
        _Pragma("unroll")                                                          \
        for (int nb = 0; nb < 4; ++nb) {                                           \
            s_[nb] = vzero;                                                        \
            int krow = (nb << 4) + lr;                                             \
            _Pragma("unroll")                                                      \
            for (int kf = 0; kf < 4; ++kf) {                                       \
                int ba = ((krow << 8) + (((kf << 5) + (lg << 3)) << 1))            \
                         ^ ((krow & 7) << 4);                                      \
                bf16x8 kfr = *(const bf16x8*)((const char*)Kbuf[BUF] + ba);        \
                s_[nb] = mfma16(kfr, qf[kf], s_[nb]);                              \
            }                                                                      \
        }                                                                          \
        __builtin_amdgcn_s_setprio(0);                                             \
        float sv[4][4];                                                            \
        _Pragma("unroll")                                                          \
        for (int nb = 0; nb < 4; ++nb) {                                           \
            float bb[4] = {BR[nb].x, BR[nb].y, BR[nb].z, BR[nb].w};                \
            _Pragma("unroll")                                                      \
            for (int r = 0; r < 4; ++r) {                                          \
                float x2 = fmaf(s_[nb][r], 0.08838834764831845f, bb[r]);           \
                sv[nb][r] = ((MR[nb] >> (r * 8)) & 0xffu) ? x2 : NEGF;             \
            }                                                                      \
        }                                                                          \
        float mt = sv[0][0];                                                       \
        _Pragma("unroll")                                                          \
        for (int nb = 0; nb < 4; ++nb)                                             \
            _Pragma("unroll")                                                      \
            for (int r = 0; r < 4; ++r) mt = fmaxf(mt, sv[nb][r]);                 \
        mt = fmaxf(mt, __shfl_xor(mt, 16, 64));                                    \
        mt = fmaxf(mt, __shfl_xor(mt, 32, 64));                                    \
        float mn = fmaxf(m_run, mt);                                               \
        float al = __expf(m_run - mn);                                             \
        m_run = mn;                                                                \
        float rs = 0.f;                                                            \
        _Pragma("unroll")                                                          \
        for (int nb = 0; nb < 4; ++nb)                                             \
            _Pragma("unroll")                                                      \
            for (int r = 0; r < 4; ++r) {                                          \
                sv[nb][r] = __expf(sv[nb][r] - m_run);                             \
                rs += sv[nb][r];                                                   \
            }                                                                      \
        rs += __shfl_xor(rs, 16, 64);                                              \
        rs += __shfl_xor(rs, 32, 64);                                              \
        l_run = l_run * al + rs;                                                   \
        float alm[4];                                                              \
        _Pragma("unroll")                                                          \
        for (int r = 0; r < 4; ++r) alm[r] = __shfl(al, (lg << 2) + r, 64);        \
        _Pragma("unroll")                                                          \
        for (int nb2 = 0; nb2 < 8; ++nb2) {                                        \
            o[nb2][0] *= alm[0]; o[nb2][1] *= alm[1];                              \
            o[nb2][2] *= alm[2]; o[nb2][3] *= alm[3];                              \
        }                                                                          \
        _Pragma("unroll")                                                          \
        for (int nb = 0; nb < 4; ++nb)                                             \
            _Pragma("unroll")                                                      \
            for (int r = 0; r < 4; ++r)                                            \
                Plds[w][lr * 72 + (nb << 4) + (lg << 2) + r] = f32_to_bf16(sv[nb][r]); \
        __builtin_amdgcn_s_setprio(1);                                             \
        _Pragma("unroll")                                                          \
        for (int kf2 = 0; kf2 < 2; ++kf2) {                                        \
            bf16x8 pf = *(const bf16x8*)&Plds[w][lr * 72 + (kf2 << 5) + (lg << 3)]; \
            _Pragma("unroll")                                                      \
            for (int nb2 = 0; nb2 < 8; ++nb2) {                                    \
                int dh = (nb2 << 4) + lr;                                          \
                int ba = ((dh << 7) + (((kf2 << 5) + (lg << 3)) << 1))             \
                         ^ ((dh & 7) << 4);                                        \
                bf16x8 vf = *(const bf16x8*)((const char*)Vbuf[BUF] + ba);         \
                o[nb2] = mfma16(pf, vf, o[nb2]);                                   \
            }                                                                      \
        }                                                                          \
        __builtin_amdgcn_s_setprio(0);                                             \
    } while (0)

    STAGE_KV(0, 0);
    LOAD_BM(br0, mr0, 0);

#pragma unroll 1
    for (int kt = 0; kt < 16; kt += 2) {
        __syncthreads();
        STAGE_KV(kt + 1, 1);
        LOAD_BM(br1, mr1, kt + 1);
        COMPUTE(0, br0, mr0);
        __syncthreads();
        if (kt < 14) {
            STAGE_KV(kt + 2, 0);
            LOAD_BM(br0, mr0, kt + 2);
        }
        COMPUTE(1, br1, mr1);
    }

    float lm[4];
#pragma unroll
    for (int r = 0; r < 4; ++r) lm[r] = __shfl(l_run, (lg << 2) + r, 64);
#pragma unroll
    for (int r = 0; r < 4; ++r) {
        float inv = lm[r] > 0.f ? 1.0f / lm[r] : 0.f;
        int q = q0 + (lg << 2) + r;
        unsigned short* cp = ctx + ((size_t)(b * S_ + q)) * D_ + h * DH_ + lr;
#pragma unroll
        for (int nb2 = 0; nb2 < 8; ++nb2)
            cp[nb2 * 16] = f32_to_bf16(o[nb2][r] * inv);
    }
#undef STAGE_KV
#undef LOAD_BM
#undef COMPUTE
}

// ---------------------------------------------------------------------------
extern "C" void kernel_launch(void* const* d_in, const int* in_sizes, int n_in,
                              void* d_out, int out_size, void* d_ws, size_t ws_size,
                              hipStream_t stream) {
    const float* hq   = (const float*)d_in[0];
    const float* hkv  = (const float*)d_in[1];
    const void*  mask = d_in[2];
    const float* bias = (const float*)d_in[3];
    const float* Wq   = (const float*)d_in[4];
    const float* Wk   = (const float*)d_in[5];
    const float* Wv   = (const float*)d_in[6];
    const float* Wo   = (const float*)d_in[7];
    float* out = (float*)d_out;

    char* ws = (char*)d_ws;
    unsigned char* mask_c = (unsigned char*)ws;                        // 2 MB
    int* flag             = (int*)(ws + (2u << 20));
    unsigned short* hq_b  = (unsigned short*)(ws + (2u << 20) + 4096); // 16 MB
    unsigned short* hkv_b = hq_b + ((size_t)1 << 23);                  // 16 MB
    unsigned short* WTq   = hkv_b + ((size_t)1 << 23);                 // 32 MB
    unsigned short* WTo   = WTq + ((size_t)1 << 24);                   // 32 MB
    unsigned short* WTkv  = WTo + ((size_t)1 << 24);                   // 64 MB
    unsigned short* Qws   = WTkv + ((size_t)1 << 25);                  // 16 MB
    unsigned short* KVws  = Qws + ((size_t)1 << 23);                   // 32 MB
    unsigned short* Cws   = KVws + ((size_t)1 << 24);                  // 16 MB
    unsigned short* Vtw   = Cws + ((size_t)1 << 23);                   // 16 MB
    float* Pws            = (float*)(Vtw + ((size_t)1 << 23));         // 64 MB

    detect_mask_kernel<<<1, 64, 0, stream>>>((const unsigned char*)mask, flag);
    canon_mask_kernel<<<8192, 256, 0, stream>>>(mask, flag, mask_c, B_ * S_ * S_);
    cvt2_bf16_kernel<<<16384, 256, 0, stream>>>(hq, hkv, hq_b, hkv_b);
    transpose_all_kernel<<<16384, 256, 0, stream>>>(Wq, Wk, Wv, Wo, WTq, WTkv, WTo);

    gemm_qkv_kernel<<<512, 512, 0, stream>>>(hq_b, WTq, Pws, hkv_b, WTkv, KVws);
    reduce_q_kernel<<<(M_ * D_) / 1024, 256, 0, stream>>>(Pws, Qws);

    vt_kernel<<<B_ * H_ * 16 * 2, 256, 0, stream>>>(KVws, Vtw);
    attn_kernel<<<B_ * H_ * (S_ / 64), 256, 0, stream>>>(Qws, KVws, Vtw, bias, mask_c, Cws);

    gemm_o_kernel<<<256, 512, 0, stream>>>(Cws, WTo, Pws);
    reduce_o_kernel<<<(M_ * D_) / 1024, 256, 0, stream>>>(Pws, out);
}